// Round 3
// baseline (818.834 us; speedup 1.0000x reference)
//
#include <hip/hip_runtime.h>
#include <cstdint>
#include <cstddef>

// ConvVFE: voxelize -> per-voxel mean -> MLP(10->32)+BN+ReLU -> voxel max
// -> concat -> MLP(64->128)+BN+ReLU -> voxel max ; plus voxel coords.
//
// R7: R6 counters: kB 204us latency-bound (MfmaUtil 6.3%, VALU 26%, occ 22%,
// WRITE 123MB = XpL/XpU eviction). Changes:
//  - XpU (64MB broadcast) -> compact xmaxV[V][32] bf16 (2MB, L2); kB gathers
//    upper frag via vS[row].
//  - XpL stores RAW y0; BN0+relu applied in registers in k8 and on kB's
//    A-frag (bit-identical). k8 read-only, writes 2MB.
//  - k1 accumulates voxel xyz sums (atomic); mean in k2c; k3+k4+k5 fused
//    into k35 (y0 written directly to sorted slot; pts4/ord deleted).
//  - kB gather rewritten as sequential segmented scan (one channel x half-
//    tile per thread, wave-uniform flush), BN1 stats from acc registers,
//    partials -> sPart -> k_red1.
//  - kB software pipeline: prefetch next tile frags right after barrier #2
//    so the gather phase hides the load latency (barriers stay plain
//    __syncthreads; drains are cheap because loads age through gather).
//  - els bf16 stride 132: conflict-free staging and gather, 17KB LDS.

constexpr int M_IDS  = 220000;
constexpr int CH     = 256;
constexpr int NCHUNK = (M_IDS + CH - 1) / CH;   // 860
constexpr int NB1    = 1536;                    // kB grid / stats partials
constexpr int ELS2   = 132;                     // els row stride (u16)

typedef __attribute__((ext_vector_type(8))) __bf16          bf16x8;
typedef __attribute__((ext_vector_type(8))) unsigned short  u16x8;
typedef __attribute__((ext_vector_type(4))) float           f32x4;

union U8 { u16x8 u; bf16x8 b; };

__device__ __forceinline__ uint16_t f2b(float f) {
    uint32_t u = __float_as_uint(f);
    u += 0x7fffu + ((u >> 16) & 1u);
    return (uint16_t)(u >> 16);
}
__device__ __forceinline__ float b2f(uint16_t h) {
    return __uint_as_float(((uint32_t)h) << 16);
}

__device__ __forceinline__ f32x4 mfma16(bf16x8 a, bf16x8 b, f32x4 c) {
    return __builtin_amdgcn_mfma_f32_16x16x32_bf16(a, b, c, 0, 0, 0);
}

// ---------------------------------------------------------------- k1: merge id + histogram + xyz sums
__global__ void k1_count(const float* __restrict__ pts, int* __restrict__ inv,
                         int* __restrict__ cnt, float* __restrict__ sums, int N)
{
    int i = blockIdx.x * blockDim.x + threadIdx.x;
    if (i >= N) return;
    const float* p = pts + (size_t)i * 5;
    float b = p[0], x = p[1], y = p[2], z = p[3];
    float fx = floorf((x - 0.0f) / 0.32f);
    float fy = floorf((y + 40.0f) / 0.32f);
    float fz = floorf((z + 3.0f) / 4.0f);
    bool ok = (fx >= 0.0f) && (fx < 220.0f) && (fy >= 0.0f) && (fy < 250.0f) &&
              (fz >= 0.0f) && (fz < 1.0f);
    if (!ok) { inv[i] = -1; return; }
    int m = (int)b * 55000 + (int)fx * 250 + (int)fy + (int)fz;
    inv[i] = m;
    atomicAdd(&cnt[m], 1);
    atomicAdd(&sums[(size_t)m * 4 + 0], x);
    atomicAdd(&sums[(size_t)m * 4 + 1], y);
    atomicAdd(&sums[(size_t)m * 4 + 2], z);
}

// ---------------------------------------------------------------- k2: two-level scans
__global__ void k2a_tot(const int* __restrict__ cnt, int* __restrict__ totO,
                        int* __restrict__ totC, int* __restrict__ np)
{
    __shared__ int so[CH], sc[CH];
    int t = threadIdx.x;
    int id = blockIdx.x * CH + t;
    int c = (id < M_IDS) ? cnt[id] : 0;
    so[t] = (c > 0) ? 1 : 0;
    sc[t] = c;
    __syncthreads();
    for (int s = CH / 2; s > 0; s >>= 1) {
        if (t < s) { so[t] += so[t + s]; sc[t] += sc[t + s]; }
        __syncthreads();
    }
    if (t == 0) { totO[blockIdx.x] = so[0]; totC[blockIdx.x] = sc[0]; atomicAdd(np, sc[0]); }
}

__global__ void k2b_scan(const int* __restrict__ totO, const int* __restrict__ totC,
                         int* __restrict__ baseO, int* __restrict__ baseC)
{
    __shared__ int a[1024], bb[1024];
    int t = threadIdx.x;
    int vo = (t < NCHUNK) ? totO[t] : 0;
    int vc = (t < NCHUNK) ? totC[t] : 0;
    a[t] = vo; bb[t] = vc;
    __syncthreads();
    for (int off = 1; off < 1024; off <<= 1) {
        int xa = (t >= off) ? a[t - off] : 0;
        int xb = (t >= off) ? bb[t - off] : 0;
        __syncthreads();
        a[t] += xa; bb[t] += xb;
        __syncthreads();
    }
    baseO[t] = a[t] - vo;   // exclusive
    baseC[t] = bb[t] - vc;
}

__global__ void k2c_index(const int* __restrict__ cnt, const int* __restrict__ baseO,
                          const int* __restrict__ baseC, const float* __restrict__ sums,
                          int* __restrict__ idxArr, int* __restrict__ bOff,
                          int* __restrict__ vOff, int* __restrict__ vCnt,
                          float4* __restrict__ meanArr, float* __restrict__ outCoords)
{
    __shared__ int a[CH], bb[CH];
    int t = threadIdx.x;
    int id = blockIdx.x * CH + t;
    int c = (id < M_IDS) ? cnt[id] : 0;
    int occ = (c > 0) ? 1 : 0;
    a[t] = occ; bb[t] = c;
    __syncthreads();
    for (int off = 1; off < CH; off <<= 1) {
        int xa = (t >= off) ? a[t - off] : 0;
        int xb = (t >= off) ? bb[t - off] : 0;
        __syncthreads();
        a[t] += xa; bb[t] += xb;
        __syncthreads();
    }
    if (id >= M_IDS) return;
    int g  = baseO[blockIdx.x] + a[t] - occ;
    int bo = baseC[blockIdx.x] + bb[t] - c;
    idxArr[id] = g;
    bOff[id]   = bo;
    if (occ) {
        vOff[g] = bo;
        vCnt[g] = c;
        float ic = 1.0f / (float)c;
        const float* sm = sums + (size_t)id * 4;
        meanArr[g] = make_float4(sm[0] * ic, sm[1] * ic, sm[2] * ic, 0.0f);
        int b2 = id / 55000;
        int rm = id % 55000;
        int cx = rm / 250;
        int cy = rm % 250;
        outCoords[(size_t)g * 4 + 0] = (float)b2;
        outCoords[(size_t)g * 4 + 1] = 0.0f;
        outCoords[(size_t)g * 4 + 2] = (float)cy;
        outCoords[(size_t)g * 4 + 3] = (float)cx;
    }
}

// ---------------------------------------------------------------- k35: order + y0 = feats @ w0 (raw, bf16) + BN0 stats
__global__ __launch_bounds__(256)
void k35_feat(const float* __restrict__ pts, const float* __restrict__ w0,
              const int* __restrict__ inv, const int* __restrict__ bOff,
              const int* __restrict__ idxArr, const float4* __restrict__ meanArr,
              int* __restrict__ cursor, uint16_t* __restrict__ XpL,
              int* __restrict__ vS, float* __restrict__ stats0, int N)
{
    __shared__ float sl[64];
    int t = threadIdx.x;
    if (t < 64) sl[t] = 0.0f;
    __syncthreads();
    float s[32], q[32];
#pragma unroll
    for (int c = 0; c < 32; c++) { s[c] = 0.0f; q[c] = 0.0f; }

    for (int i = blockIdx.x * 256 + t; i < N; i += gridDim.x * 256) {
        int m = inv[i];
        if (m < 0) continue;
        const float* p = pts + (size_t)i * 5;
        float x = p[1], y = p[2], z = p[3], it = p[4];
        int slot = atomicAdd(&cursor[m], 1);
        int j = bOff[m] + slot;
        int v = idxArr[m];
        float4 mn = meanArr[v];
        float fx = floorf(x / 0.32f);
        float fy = floorf((y + 40.0f) / 0.32f);
        float f[10];
        f[0] = x; f[1] = y; f[2] = z; f[3] = it;
        f[4] = x - mn.x; f[5] = y - mn.y; f[6] = z - mn.z;
        f[7] = x - (fx * 0.32f + 0.16f);
        f[8] = y - (fy * 0.32f - 39.84f);
        f[9] = z + 1.0f;
        float y0[32];
#pragma unroll
        for (int c = 0; c < 32; c++) y0[c] = 0.0f;
#pragma unroll
        for (int d = 0; d < 10; d++) {
            float fd = f[d];
#pragma unroll
            for (int c = 0; c < 32; c++) y0[c] += fd * w0[d * 32 + c];
        }
        uint32_t pk[16];
#pragma unroll
        for (int k = 0; k < 16; k++)
            pk[k] = (uint32_t)f2b(y0[2 * k]) | ((uint32_t)f2b(y0[2 * k + 1]) << 16);
        uint4* rp = (uint4*)(XpL + (size_t)j * 32);
        rp[0] = make_uint4(pk[0], pk[1], pk[2], pk[3]);
        rp[1] = make_uint4(pk[4], pk[5], pk[6], pk[7]);
        rp[2] = make_uint4(pk[8], pk[9], pk[10], pk[11]);
        rp[3] = make_uint4(pk[12], pk[13], pk[14], pk[15]);
        vS[j] = v;
#pragma unroll
        for (int c = 0; c < 32; c++) { s[c] += y0[c]; q[c] += y0[c] * y0[c]; }
    }

    int lane = t & 63;
#pragma unroll
    for (int c = 0; c < 32; c++) {
#pragma unroll
        for (int m2 = 1; m2 < 64; m2 <<= 1) {
            s[c] += __shfl_xor(s[c], m2);
            q[c] += __shfl_xor(q[c], m2);
        }
        if (lane == c) { atomicAdd(&sl[c], s[c]); atomicAdd(&sl[32 + c], q[c]); }
    }
    __syncthreads();
    if (t < 64) atomicAdd(&stats0[t], sl[t]);
}

// ---------------------------------------------------------------- BN finalize
__global__ void k_bnfin(const float* __restrict__ stats, const int* __restrict__ np,
                        const float* __restrict__ g, const float* __restrict__ b,
                        float* __restrict__ sb, int C)
{
    int c = blockIdx.x * blockDim.x + threadIdx.x;
    if (c >= C) return;
    float n   = (float)(*np);
    float mu  = stats[c] / n;
    float var = stats[C + c] / n - mu * mu;
    float s   = g[c] / sqrtf(var + 1e-3f);
    sb[c]     = s;
    sb[C + c] = b[c] - mu * s;
}

// ---------------------------------------------------------------- k8: BN0(reg) + voxel max -> compact xmaxV (bf16)
__global__ __launch_bounds__(256)
void k8_xmax(const uint16_t* __restrict__ XpL, const int* __restrict__ vOff,
             const int* __restrict__ vCnt, const float* __restrict__ sb0,
             uint32_t* __restrict__ xmaxV, int V)
{
    int t = threadIdx.x;
    int g = blockIdx.x * 4 + (t >> 6);
    if (g >= V) return;
    int lane = t & 63;
    int c2 = lane & 15, h = lane >> 4;   // c2: u32 pair of channels, h: row phase
    int ch0 = c2 * 2;
    float sA = sb0[ch0],     bA = sb0[32 + ch0];
    float sB = sb0[ch0 + 1], bB = sb0[33 + ch0];
    int off = vOff[g], n = vCnt[g];
    float m0 = 0.0f, m1 = 0.0f;          // relu >= 0
    for (int i = h; i < n; i += 4) {
        uint32_t u = *(const uint32_t*)(XpL + (size_t)(off + i) * 32 + ch0);
        float e0 = fmaxf(b2f((uint16_t)u) * sA + bA, 0.0f);
        float e1 = fmaxf(b2f((uint16_t)(u >> 16)) * sB + bB, 0.0f);
        m0 = fmaxf(m0, e0);
        m1 = fmaxf(m1, e1);
    }
    m0 = fmaxf(m0, __shfl_xor(m0, 16)); m0 = fmaxf(m0, __shfl_xor(m0, 32));
    m1 = fmaxf(m1, __shfl_xor(m1, 16)); m1 = fmaxf(m1, __shfl_xor(m1, 32));
    if (h == 0)
        xmaxV[(size_t)g * 16 + c2] = (uint32_t)f2b(m0) | ((uint32_t)f2b(m1) << 16);
}

// ---------------------------------------------------------------- W frags: bf16 hi/lo split of w1
__device__ __forceinline__ void load_wsplit(const float* __restrict__ w1, int cb,
                                            int l15, int lg, bf16x8* Bhi, bf16x8* Blo)
{
    int col = cb + l15;
    int kr  = lg * 8;
#pragma unroll
    for (int nb = 0; nb < 4; nb++) {
#pragma unroll
        for (int ks = 0; ks < 2; ks++) {
            U8 h, l;
#pragma unroll
            for (int jj = 0; jj < 8; jj++) {
                float w = w1[(ks * 32 + kr + jj) * 128 + col + nb * 16];
                uint16_t hb = f2b(w);
                h.u[jj] = hb;
                l.u[jj] = f2b(w - b2f(hb));
            }
            Bhi[nb * 2 + ks] = h.b;
            Blo[nb * 2 + ks] = l.b;
        }
    }
}

// ---------------------------------------------------------------- kB: pipelined MFMA GEMM + segmented voxel max + BN1 stats
__global__ __launch_bounds__(256)
void kB_mapply(const uint16_t* __restrict__ XpL, const uint16_t* __restrict__ xmaxV,
               const float* __restrict__ w1, const float* __restrict__ g1,
               const int* __restrict__ vS, const int* __restrict__ vOff,
               const int* __restrict__ vCnt, const int* __restrict__ np,
               const float* __restrict__ sb0, unsigned int* __restrict__ out,
               float* __restrict__ sPart, int ntiles)
{
    __shared__ uint16_t els[64 * ELS2];  // bf16 y-tile (stride 132: conflict-free)
    __shared__ int sVS[64];
    int t = threadIdx.x;
    int wv = t >> 6, lane = t & 63;
    int l15 = lane & 15, lg = lane >> 4;
    int rowSel = wv & 1;
    int cb     = (wv >> 1) * 64;

    bf16x8 Bhi[8], Blo[8];
    load_wsplit(w1, cb, l15, lg, Bhi, Blo);

    float sc0[8], bc0[8];                // BN0 for this wave's K-slice
#pragma unroll
    for (int j = 0; j < 8; j++) { sc0[j] = sb0[lg * 8 + j]; bc0[j] = sb0[32 + lg * 8 + j]; }

    int nv = *np;
    int cg = t & 127;                    // gather channel
    int half = t >> 7;                   // gather half-tile (rows half*32..+32)
    int r0h = half * 32;
    uint32_t sgnm = (g1[cg] < 0.0f) ? 0x80000000u : 0u;
    float s[4] = {0.f, 0.f, 0.f, 0.f}, q[4] = {0.f, 0.f, 0.f, 0.f};

    U8 pL[2], pU[2];
    int pvs = 0;
    int tile = blockIdx.x;
    if (tile < ntiles && tile * 64 < nv) {          // prologue loads
        int tb2 = tile * 64;
        int r0 = tb2 + rowSel * 32 + l15;
        int v0 = vS[r0];
        int v1 = vS[r0 + 16];
        pL[0].u = *(const u16x8*)(XpL + (size_t)r0 * 32 + lg * 8);
        pL[1].u = *(const u16x8*)(XpL + (size_t)(r0 + 16) * 32 + lg * 8);
        if (t < 64) pvs = vS[tb2 + t];
        v0 = (r0 < nv) ? v0 : 0;
        v1 = (r0 + 16 < nv) ? v1 : 0;
        pU[0].u = *(const u16x8*)(xmaxV + (size_t)v0 * 32 + lg * 8);
        pU[1].u = *(const u16x8*)(xmaxV + (size_t)v1 * 32 + lg * 8);
    }

    for (; tile < ntiles; tile += gridDim.x) {
        int tb = tile * 64;
        if (tb >= nv) break;             // uniform across block
        // decode: BN0+relu on lower frag, zero-clamp padding rows
        U8 aL[2], aU[2];
#pragma unroll
        for (int m = 0; m < 2; m++) {
            int r = tb + rowSel * 32 + m * 16 + l15;
            bool live = (r < nv);
#pragma unroll
            for (int j = 0; j < 8; j++) {
                float e = fmaxf(b2f(pL[m].u[j]) * sc0[j] + bc0[j], 0.0f);
                aL[m].u[j] = live ? f2b(e) : (uint16_t)0;
                aU[m].u[j] = live ? pU[m].u[j] : (uint16_t)0;
            }
        }
        f32x4 acc[2][4];
#pragma unroll
        for (int m = 0; m < 2; m++)
#pragma unroll
            for (int nb = 0; nb < 4; nb++)
                acc[m][nb] = (f32x4){0.f, 0.f, 0.f, 0.f};
#pragma unroll
        for (int m = 0; m < 2; m++) {
#pragma unroll
            for (int nb = 0; nb < 4; nb++) {
                acc[m][nb] = mfma16(aL[m].b, Bhi[nb * 2],     acc[m][nb]);
                acc[m][nb] = mfma16(aL[m].b, Blo[nb * 2],     acc[m][nb]);
                acc[m][nb] = mfma16(aU[m].b, Bhi[nb * 2 + 1], acc[m][nb]);
                acc[m][nb] = mfma16(aU[m].b, Blo[nb * 2 + 1], acc[m][nb]);
            }
        }
        // BN1 stats from acc (each row<nv x channel counted exactly once)
#pragma unroll
        for (int m = 0; m < 2; m++)
#pragma unroll
            for (int nb = 0; nb < 4; nb++)
#pragma unroll
                for (int r = 0; r < 4; r++) {
                    float y = acc[m][nb][r];
                    s[nb] += y; q[nb] += y * y;
                }
        __syncthreads();                 // B1: prev gather readers done
        if (t < 64) sVS[t] = pvs;
#pragma unroll
        for (int m = 0; m < 2; m++) {
            int rloc = rowSel * 32 + m * 16 + lg * 4;
#pragma unroll
            for (int nb = 0; nb < 4; nb++) {
                int c = cb + nb * 16 + l15;
#pragma unroll
                for (int r = 0; r < 4; r++)
                    els[(rloc + r) * ELS2 + c] = f2b(acc[m][nb][r]);
            }
        }
        __syncthreads();                 // B2: els/sVS visible
        // prefetch next tile (latency hides under gather; next B1 drain is free)
        int tp = tile + gridDim.x;
        if (tp < ntiles && tp * 64 < nv) {
            int tb2 = tp * 64;
            int r0 = tb2 + rowSel * 32 + l15;
            int v0 = vS[r0];
            int v1 = vS[r0 + 16];
            pL[0].u = *(const u16x8*)(XpL + (size_t)r0 * 32 + lg * 8);
            pL[1].u = *(const u16x8*)(XpL + (size_t)(r0 + 16) * 32 + lg * 8);
            if (t < 64) pvs = vS[tb2 + t];
            v0 = (r0 < nv) ? v0 : 0;
            v1 = (r0 + 16 < nv) ? v1 : 0;
            pU[0].u = *(const u16x8*)(xmaxV + (size_t)v0 * 32 + lg * 8);
            pU[1].u = *(const u16x8*)(xmaxV + (size_t)v1 * 32 + lg * 8);
        }
        // gather: sequential segmented max, one channel x half-tile per thread
        int lastRow = nv - 1 - tb; if (lastRow > 63) lastRow = 63;
        int r1h = (r0h + 32 <= lastRow + 1) ? (r0h + 32) : (lastRow + 1);
        if (r0h < r1h) {
            int curg = sVS[r0h];
            float mx = __uint_as_float(0xff800000u);
            for (int p2 = r0h; p2 < r1h; p2++) {
                int vg = sVS[p2];        // wave-uniform
                if (vg != curg) {        // flush (wave-uniform branch)
                    int offv = vOff[curg], endv = offv + vCnt[curg];
                    uint32_t u = __float_as_uint(mx);
                    uint32_t enc = (u & 0x80000000u) ? ~u : (u | 0x80000000u);
                    size_t oa = (size_t)curg * 128 + cg;
                    if (offv >= tb + r0h && endv <= tb + r1h) out[oa] = enc;
                    else atomicMax(&out[oa], enc);
                    curg = vg;
                    mx = __uint_as_float(0xff800000u);
                }
                uint32_t raw = ((uint32_t)els[p2 * ELS2 + cg]) << 16;
                mx = fmaxf(mx, __uint_as_float(raw ^ sgnm));
            }
            int offv = vOff[curg], endv = offv + vCnt[curg];
            uint32_t u = __float_as_uint(mx);
            uint32_t enc = (u & 0x80000000u) ? ~u : (u | 0x80000000u);
            size_t oa = (size_t)curg * 128 + cg;
            if (offv >= tb + r0h && endv <= tb + r1h) out[oa] = enc;
            else atomicMax(&out[oa], enc);
        }
    }
    // BN1 partials: wave-reduce, stage via LDS, one plain store per channel
    __syncthreads();
    float* fl = (float*)els;
#pragma unroll
    for (int nb = 0; nb < 4; nb++) {
        s[nb] += __shfl_xor(s[nb], 16); s[nb] += __shfl_xor(s[nb], 32);
        q[nb] += __shfl_xor(q[nb], 16); q[nb] += __shfl_xor(q[nb], 32);
    }
    if (lane < 16) {
#pragma unroll
        for (int nb = 0; nb < 4; nb++) {
            int ch = cb + nb * 16 + lane;
            fl[rowSel * 128 + ch]       = s[nb];
            fl[256 + rowSel * 128 + ch] = q[nb];
        }
    }
    __syncthreads();
    if (t < 128) {
        sPart[(size_t)t * NB1 + blockIdx.x]         = fl[t] + fl[128 + t];
        sPart[(size_t)(128 + t) * NB1 + blockIdx.x] = fl[256 + t] + fl[384 + t];
    }
}

// ---------------------------------------------------------------- reduce stat partials
__global__ void k_red1(const float* __restrict__ part, float* __restrict__ stats1)
{
    __shared__ float red[4];
    int o = blockIdx.x, t = threadIdx.x;
    float s = 0.0f;
    for (int k = t; k < NB1; k += 256) s += part[(size_t)o * NB1 + k];
#pragma unroll
    for (int m = 1; m < 64; m <<= 1) s += __shfl_xor(s, m);
    if ((t & 63) == 0) red[t >> 6] = s;
    __syncthreads();
    if (t == 0) stats1[o] = red[0] + red[1] + red[2] + red[3];
}

// ---------------------------------------------------------------- k_final: decode + BN1 + ReLU over out
__global__ void k_final(unsigned int* __restrict__ out, const float* __restrict__ sb1,
                        const float* __restrict__ g1, int n4)
{
    int i = blockIdx.x * 256 + threadIdx.x;
    if (i >= n4) return;
    uint4 e = ((const uint4*)out)[i];
    int c0 = (i & 31) * 4;
    uint32_t ee[4] = {e.x, e.y, e.z, e.w};
    float r[4];
#pragma unroll
    for (int j = 0; j < 4; j++) {
        int c = c0 + j;
        uint32_t u = (ee[j] & 0x80000000u) ? (ee[j] ^ 0x80000000u) : ~ee[j];
        float f = __uint_as_float(u);
        uint32_t sg = (g1[c] < 0.0f) ? 0x80000000u : 0u;
        f = __uint_as_float(__float_as_uint(f) ^ sg);   // unflip for s<0 channels
        r[j] = fmaxf(f * sb1[c] + sb1[128 + c], 0.0f);
    }
    ((float4*)out)[i] = make_float4(r[0], r[1], r[2], r[3]);
}

// ---------------------------------------------------------------- launch
extern "C" void kernel_launch(void* const* d_in, const int* in_sizes, int n_in,
                              void* d_out, int out_size, void* d_ws, size_t ws_size,
                              hipStream_t stream)
{
    const float* pts = (const float*)d_in[0];
    const float* w0  = (const float*)d_in[1];
    const float* g0  = (const float*)d_in[2];
    const float* b0  = (const float*)d_in[3];
    const float* w1  = (const float*)d_in[4];
    const float* g1  = (const float*)d_in[5];
    const float* b1  = (const float*)d_in[6];

    int N      = in_sizes[0] / 5;
    int V      = out_size / 132;
    int Npad   = (N + 255) & ~255;
    int ntiles = Npad / 64;

    char* ws = (char*)d_ws;
    size_t off = 0;
    auto alloc = [&](size_t bytes) { size_t r = off; off = (off + bytes + 255) & ~(size_t)255; return r; };

    int*    inv     = (int*)(ws + alloc((size_t)N * 4));
    int*    vS      = (int*)(ws + alloc((size_t)Npad * 4));
    size_t  zOff    = off;                                   // zero block start
    int*    cnt     = (int*)(ws + alloc((size_t)M_IDS * 4));
    int*    cursor  = (int*)(ws + alloc((size_t)M_IDS * 4));
    float*  stats   = (float*)(ws + alloc(320 * 4));         // bn0: 64 | bn1: 256
    int*    np      = (int*)(ws + alloc(4));
    float*  sums    = (float*)(ws + alloc((size_t)M_IDS * 16));
    size_t  zBytes  = off - zOff;
    int*    bOff    = (int*)(ws + alloc((size_t)M_IDS * 4));
    int*    idxArr  = (int*)(ws + alloc((size_t)M_IDS * 4));
    int*    vOff    = (int*)(ws + alloc((size_t)M_IDS * 4));
    int*    vCnt    = (int*)(ws + alloc((size_t)M_IDS * 4));
    int*    totO    = (int*)(ws + alloc(1024 * 4));
    int*    totC    = (int*)(ws + alloc(1024 * 4));
    int*    baseO   = (int*)(ws + alloc(1024 * 4));
    int*    baseC   = (int*)(ws + alloc(1024 * 4));
    float*  sb0     = (float*)(ws + alloc(64 * 4));
    float*  sb1     = (float*)(ws + alloc(256 * 4));
    float*  sPart   = (float*)(ws + alloc((size_t)256 * NB1 * 4));
    float4* meanArr = (float4*)(ws + alloc((size_t)V * 16));
    uint16_t* XpL   = (uint16_t*)(ws + alloc((size_t)Npad * 32 * 2));
    uint16_t* xmaxV = (uint16_t*)(ws + alloc((size_t)V * 32 * 2));
    (void)ws_size;

    hipMemsetAsync(ws + zOff, 0, zBytes, stream);
    hipMemsetAsync(d_out, 0, (size_t)V * 128 * 4, stream);

    int blocksN = (N + 255) / 256;
    float* outF = (float*)d_out;

    k1_count<<<blocksN, 256, 0, stream>>>(pts, inv, cnt, sums, N);
    k2a_tot<<<NCHUNK, CH, 0, stream>>>(cnt, totO, totC, np);
    k2b_scan<<<1, 1024, 0, stream>>>(totO, totC, baseO, baseC);
    k2c_index<<<NCHUNK, CH, 0, stream>>>(cnt, baseO, baseC, sums, idxArr, bOff,
                                         vOff, vCnt, meanArr,
                                         outF + (size_t)V * 128);
    k35_feat<<<1024, 256, 0, stream>>>(pts, w0, inv, bOff, idxArr, meanArr,
                                       cursor, XpL, vS, stats, N);
    k_bnfin<<<1, 32, 0, stream>>>(stats, np, g0, b0, sb0, 32);
    k8_xmax<<<(V + 3) / 4, 256, 0, stream>>>(XpL, vOff, vCnt, sb0,
                                             (uint32_t*)xmaxV, V);
    kB_mapply<<<NB1, 256, 0, stream>>>(XpL, xmaxV, w1, g1, vS, vOff, vCnt, np,
                                       sb0, (unsigned int*)d_out, sPart, ntiles);
    k_red1<<<256, 256, 0, stream>>>(sPart, stats + 64);
    k_bnfin<<<1, 128, 0, stream>>>(stats + 64, np, g1, b1, sb1, 128);
    k_final<<<(V * 32 + 255) / 256, 256, 0, stream>>>((unsigned int*)d_out, sb1, g1, V * 32);
}

// Round 4
// 736.041 us; speedup vs baseline: 1.1125x; 1.1125x over previous
//
#include <hip/hip_runtime.h>
#include <cstdint>
#include <cstddef>

// ConvVFE: voxelize -> per-voxel mean -> MLP(10->32)+BN+ReLU -> voxel max
// -> concat -> MLP(64->128)+BN+ReLU -> voxel max ; plus voxel coords.
//
// R8: R7 regressed (kB 273us, latency-bound: MfmaUtil 4.8, VALU 32, occ 22).
// Lesson: kB time tracks per-tile serial work, not traffic. This round:
//  - kA_stats: NEW barrier-free streaming GEMM computing BN1 stats only
//    (no LDS, no syncthreads in loop, 128 rows/iter). Compiler can pipeline.
//  - kB_mapply: back to R5's proven minimal shape. XpL is post-BN0 bf16
//    again (k8 writes it back), no decode/stats/encode in kB. Applies
//    sb1+relu in regs, stages FINAL bf16 to els[64][132], R5 dynamic
//    voxel gather, plain store interior / atomicMax (>=0, memset-0) for
//    straddlers. k_final DELETED (-222MB pass).
//  - upper frag from compact xmaxV[V][32] via vS (L2-resident, -50MB/pass).
//  - pad rows auto-masked by vS==-1 (memset), no live-row branches.

constexpr int M_IDS  = 220000;
constexpr int CH     = 256;
constexpr int NCHUNK = (M_IDS + CH - 1) / CH;   // 860
constexpr int NBA    = 1024;                    // kA grid / stats partials
constexpr int NBB    = 2048;                    // kB grid
constexpr int ELS2   = 132;                     // els row stride (u16)

typedef __attribute__((ext_vector_type(8))) __bf16          bf16x8;
typedef __attribute__((ext_vector_type(8))) unsigned short  u16x8;
typedef __attribute__((ext_vector_type(4))) float           f32x4;

union U8 { u16x8 u; bf16x8 b; };

__device__ __forceinline__ uint16_t f2b(float f) {
    uint32_t u = __float_as_uint(f);
    u += 0x7fffu + ((u >> 16) & 1u);
    return (uint16_t)(u >> 16);
}
__device__ __forceinline__ float b2f(uint16_t h) {
    return __uint_as_float(((uint32_t)h) << 16);
}

__device__ __forceinline__ f32x4 mfma16(bf16x8 a, bf16x8 b, f32x4 c) {
    return __builtin_amdgcn_mfma_f32_16x16x32_bf16(a, b, c, 0, 0, 0);
}

// ---------------------------------------------------------------- k1: merge id + histogram + xyz sums
__global__ void k1_count(const float* __restrict__ pts, int* __restrict__ inv,
                         int* __restrict__ cnt, float* __restrict__ sums, int N)
{
    int i = blockIdx.x * blockDim.x + threadIdx.x;
    if (i >= N) return;
    const float* p = pts + (size_t)i * 5;
    float b = p[0], x = p[1], y = p[2], z = p[3];
    float fx = floorf((x - 0.0f) / 0.32f);
    float fy = floorf((y + 40.0f) / 0.32f);
    float fz = floorf((z + 3.0f) / 4.0f);
    bool ok = (fx >= 0.0f) && (fx < 220.0f) && (fy >= 0.0f) && (fy < 250.0f) &&
              (fz >= 0.0f) && (fz < 1.0f);
    if (!ok) { inv[i] = -1; return; }
    int m = (int)b * 55000 + (int)fx * 250 + (int)fy + (int)fz;
    inv[i] = m;
    atomicAdd(&cnt[m], 1);
    atomicAdd(&sums[(size_t)m * 4 + 0], x);
    atomicAdd(&sums[(size_t)m * 4 + 1], y);
    atomicAdd(&sums[(size_t)m * 4 + 2], z);
}

// ---------------------------------------------------------------- k2: two-level scans
__global__ void k2a_tot(const int* __restrict__ cnt, int* __restrict__ totO,
                        int* __restrict__ totC, int* __restrict__ np)
{
    __shared__ int so[CH], sc[CH];
    int t = threadIdx.x;
    int id = blockIdx.x * CH + t;
    int c = (id < M_IDS) ? cnt[id] : 0;
    so[t] = (c > 0) ? 1 : 0;
    sc[t] = c;
    __syncthreads();
    for (int s = CH / 2; s > 0; s >>= 1) {
        if (t < s) { so[t] += so[t + s]; sc[t] += sc[t + s]; }
        __syncthreads();
    }
    if (t == 0) { totO[blockIdx.x] = so[0]; totC[blockIdx.x] = sc[0]; atomicAdd(np, sc[0]); }
}

__global__ void k2b_scan(const int* __restrict__ totO, const int* __restrict__ totC,
                         int* __restrict__ baseO, int* __restrict__ baseC)
{
    __shared__ int a[1024], bb[1024];
    int t = threadIdx.x;
    int vo = (t < NCHUNK) ? totO[t] : 0;
    int vc = (t < NCHUNK) ? totC[t] : 0;
    a[t] = vo; bb[t] = vc;
    __syncthreads();
    for (int off = 1; off < 1024; off <<= 1) {
        int xa = (t >= off) ? a[t - off] : 0;
        int xb = (t >= off) ? bb[t - off] : 0;
        __syncthreads();
        a[t] += xa; bb[t] += xb;
        __syncthreads();
    }
    baseO[t] = a[t] - vo;   // exclusive
    baseC[t] = bb[t] - vc;
}

__global__ void k2c_index(const int* __restrict__ cnt, const int* __restrict__ baseO,
                          const int* __restrict__ baseC, const float* __restrict__ sums,
                          int* __restrict__ idxArr, int* __restrict__ bOff,
                          int* __restrict__ vOff, int* __restrict__ vCnt,
                          float4* __restrict__ meanArr, float* __restrict__ outCoords)
{
    __shared__ int a[CH], bb[CH];
    int t = threadIdx.x;
    int id = blockIdx.x * CH + t;
    int c = (id < M_IDS) ? cnt[id] : 0;
    int occ = (c > 0) ? 1 : 0;
    a[t] = occ; bb[t] = c;
    __syncthreads();
    for (int off = 1; off < CH; off <<= 1) {
        int xa = (t >= off) ? a[t - off] : 0;
        int xb = (t >= off) ? bb[t - off] : 0;
        __syncthreads();
        a[t] += xa; bb[t] += xb;
        __syncthreads();
    }
    if (id >= M_IDS) return;
    int g  = baseO[blockIdx.x] + a[t] - occ;
    int bo = baseC[blockIdx.x] + bb[t] - c;
    idxArr[id] = g;
    bOff[id]   = bo;
    if (occ) {
        vOff[g] = bo;
        vCnt[g] = c;
        float ic = 1.0f / (float)c;
        const float* sm = sums + (size_t)id * 4;
        meanArr[g] = make_float4(sm[0] * ic, sm[1] * ic, sm[2] * ic, 0.0f);
        int b2 = id / 55000;
        int rm = id % 55000;
        int cx = rm / 250;
        int cy = rm % 250;
        outCoords[(size_t)g * 4 + 0] = (float)b2;
        outCoords[(size_t)g * 4 + 1] = 0.0f;
        outCoords[(size_t)g * 4 + 2] = (float)cy;
        outCoords[(size_t)g * 4 + 3] = (float)cx;
    }
}

// ---------------------------------------------------------------- k35: order + y0 = feats @ w0 (raw, bf16) + BN0 stats
__global__ __launch_bounds__(256)
void k35_feat(const float* __restrict__ pts, const float* __restrict__ w0,
              const int* __restrict__ inv, const int* __restrict__ bOff,
              const int* __restrict__ idxArr, const float4* __restrict__ meanArr,
              int* __restrict__ cursor, uint16_t* __restrict__ XpL,
              int* __restrict__ vS, float* __restrict__ stats0, int N)
{
    __shared__ float sl[64];
    int t = threadIdx.x;
    if (t < 64) sl[t] = 0.0f;
    __syncthreads();
    float s[32], q[32];
#pragma unroll
    for (int c = 0; c < 32; c++) { s[c] = 0.0f; q[c] = 0.0f; }

    for (int i = blockIdx.x * 256 + t; i < N; i += gridDim.x * 256) {
        int m = inv[i];
        if (m < 0) continue;
        const float* p = pts + (size_t)i * 5;
        float x = p[1], y = p[2], z = p[3], it = p[4];
        int slot = atomicAdd(&cursor[m], 1);
        int j = bOff[m] + slot;
        int v = idxArr[m];
        float4 mn = meanArr[v];
        float fx = floorf(x / 0.32f);
        float fy = floorf((y + 40.0f) / 0.32f);
        float f[10];
        f[0] = x; f[1] = y; f[2] = z; f[3] = it;
        f[4] = x - mn.x; f[5] = y - mn.y; f[6] = z - mn.z;
        f[7] = x - (fx * 0.32f + 0.16f);
        f[8] = y - (fy * 0.32f - 39.84f);
        f[9] = z + 1.0f;
        float y0[32];
#pragma unroll
        for (int c = 0; c < 32; c++) y0[c] = 0.0f;
#pragma unroll
        for (int d = 0; d < 10; d++) {
            float fd = f[d];
#pragma unroll
            for (int c = 0; c < 32; c++) y0[c] += fd * w0[d * 32 + c];
        }
        uint32_t pk[16];
#pragma unroll
        for (int k = 0; k < 16; k++)
            pk[k] = (uint32_t)f2b(y0[2 * k]) | ((uint32_t)f2b(y0[2 * k + 1]) << 16);
        uint4* rp = (uint4*)(XpL + (size_t)j * 32);
        rp[0] = make_uint4(pk[0], pk[1], pk[2], pk[3]);
        rp[1] = make_uint4(pk[4], pk[5], pk[6], pk[7]);
        rp[2] = make_uint4(pk[8], pk[9], pk[10], pk[11]);
        rp[3] = make_uint4(pk[12], pk[13], pk[14], pk[15]);
        vS[j] = v;
#pragma unroll
        for (int c = 0; c < 32; c++) { s[c] += y0[c]; q[c] += y0[c] * y0[c]; }
    }

    int lane = t & 63;
#pragma unroll
    for (int c = 0; c < 32; c++) {
#pragma unroll
        for (int m2 = 1; m2 < 64; m2 <<= 1) {
            s[c] += __shfl_xor(s[c], m2);
            q[c] += __shfl_xor(q[c], m2);
        }
        if (lane == c) { atomicAdd(&sl[c], s[c]); atomicAdd(&sl[32 + c], q[c]); }
    }
    __syncthreads();
    if (t < 64) atomicAdd(&stats0[t], sl[t]);
}

// ---------------------------------------------------------------- BN finalize
__global__ void k_bnfin(const float* __restrict__ stats, const int* __restrict__ np,
                        const float* __restrict__ g, const float* __restrict__ b,
                        float* __restrict__ sb, int C)
{
    int c = blockIdx.x * blockDim.x + threadIdx.x;
    if (c >= C) return;
    float n   = (float)(*np);
    float mu  = stats[c] / n;
    float var = stats[C + c] / n - mu * mu;
    float s   = g[c] / sqrtf(var + 1e-3f);
    sb[c]     = s;
    sb[C + c] = b[c] - mu * s;
}

// ---------------------------------------------------------------- k8: BN0 apply (writeback) + voxel max -> xmaxV
__global__ __launch_bounds__(256)
void k8_xmax(uint16_t* __restrict__ XpL, const int* __restrict__ vOff,
             const int* __restrict__ vCnt, const float* __restrict__ sb0,
             uint32_t* __restrict__ xmaxV, int V)
{
    int t = threadIdx.x;
    int g = blockIdx.x * 4 + (t >> 6);
    if (g >= V) return;
    int lane = t & 63;
    int c2 = lane & 15, h = lane >> 4;   // c2: u32 pair of channels, h: row phase
    int ch0 = c2 * 2;
    float sA = sb0[ch0],     bA = sb0[32 + ch0];
    float sB = sb0[ch0 + 1], bB = sb0[33 + ch0];
    int off = vOff[g], n = vCnt[g];
    float m0 = 0.0f, m1 = 0.0f;          // relu >= 0
    for (int i = h; i < n; i += 4) {
        uint32_t* ap = (uint32_t*)(XpL + (size_t)(off + i) * 32 + ch0);
        uint32_t u = *ap;
        float e0 = fmaxf(b2f((uint16_t)u) * sA + bA, 0.0f);
        float e1 = fmaxf(b2f((uint16_t)(u >> 16)) * sB + bB, 0.0f);
        *ap = (uint32_t)f2b(e0) | ((uint32_t)f2b(e1) << 16);
        m0 = fmaxf(m0, e0);
        m1 = fmaxf(m1, e1);
    }
    m0 = fmaxf(m0, __shfl_xor(m0, 16)); m0 = fmaxf(m0, __shfl_xor(m0, 32));
    m1 = fmaxf(m1, __shfl_xor(m1, 16)); m1 = fmaxf(m1, __shfl_xor(m1, 32));
    if (h == 0)
        xmaxV[(size_t)g * 16 + c2] = (uint32_t)f2b(m0) | ((uint32_t)f2b(m1) << 16);
}

// ---------------------------------------------------------------- W frags: bf16 hi/lo split of w1
__device__ __forceinline__ void load_wsplit(const float* __restrict__ w1, int cb,
                                            int l15, int lg, bf16x8* Bhi, bf16x8* Blo)
{
    int col = cb + l15;
    int kr  = lg * 8;
#pragma unroll
    for (int nb = 0; nb < 4; nb++) {
#pragma unroll
        for (int ks = 0; ks < 2; ks++) {
            U8 h, l;
#pragma unroll
            for (int jj = 0; jj < 8; jj++) {
                float w = w1[(ks * 32 + kr + jj) * 128 + col + nb * 16];
                uint16_t hb = f2b(w);
                h.u[jj] = hb;
                l.u[jj] = f2b(w - b2f(hb));
            }
            Bhi[nb * 2 + ks] = h.b;
            Blo[nb * 2 + ks] = l.b;
        }
    }
}

// ---------------------------------------------------------------- frag fetch (lower from XpL, upper from xmaxV via vS)
__device__ __forceinline__ void load_afrags(const uint16_t* __restrict__ XpL,
                                            const uint16_t* __restrict__ xmaxV,
                                            const int* __restrict__ vS,
                                            int tb, int rowSel, int l15, int lg,
                                            U8* aL, U8* aU)
{
#pragma unroll
    for (int m = 0; m < 2; m++) {
        int r = tb + rowSel * 32 + m * 16 + l15;
        int v = vS[r];                   // pad rows: -1 (memset)
        if (v >= 0) {
            aL[m].u = *(const u16x8*)(XpL + (size_t)r * 32 + lg * 8);
            aU[m].u = *(const u16x8*)(xmaxV + (size_t)v * 32 + lg * 8);
        } else {
#pragma unroll
            for (int j = 0; j < 8; j++) { aL[m].u[j] = 0; aU[m].u[j] = 0; }
        }
    }
}

// ---------------------------------------------------------------- kA: streaming stats GEMM (no barriers in loop)
__global__ __launch_bounds__(256)
void kA_stats(const uint16_t* __restrict__ XpL, const uint16_t* __restrict__ xmaxV,
              const float* __restrict__ w1, const int* __restrict__ vS,
              const int* __restrict__ np, float* __restrict__ sPart, int nwin2)
{
    __shared__ float fl[512];
    int t = threadIdx.x;
    int wv = t >> 6, lane = t & 63;
    int l15 = lane & 15, lg = lane >> 4;
    int rowSel = wv & 1, cb = (wv >> 1) * 64;

    bf16x8 Bhi[8], Blo[8];
    load_wsplit(w1, cb, l15, lg, Bhi, Blo);

    int nv = *np;
    float s[4] = {0.f, 0.f, 0.f, 0.f}, q[4] = {0.f, 0.f, 0.f, 0.f};

    for (int win = blockIdx.x; win < nwin2; win += gridDim.x) {
        int wb = win * 128;
        if (wb >= nv) break;
#pragma unroll
        for (int sub = 0; sub < 2; sub++) {
            int tb = wb + sub * 64;
            U8 aL[2], aU[2];
            load_afrags(XpL, xmaxV, vS, tb, rowSel, l15, lg, aL, aU);
            f32x4 acc[2][4];
#pragma unroll
            for (int m = 0; m < 2; m++)
#pragma unroll
                for (int nb = 0; nb < 4; nb++)
                    acc[m][nb] = (f32x4){0.f, 0.f, 0.f, 0.f};
#pragma unroll
            for (int m = 0; m < 2; m++)
#pragma unroll
                for (int nb = 0; nb < 4; nb++) {
                    acc[m][nb] = mfma16(aL[m].b, Bhi[nb * 2],     acc[m][nb]);
                    acc[m][nb] = mfma16(aL[m].b, Blo[nb * 2],     acc[m][nb]);
                    acc[m][nb] = mfma16(aU[m].b, Bhi[nb * 2 + 1], acc[m][nb]);
                    acc[m][nb] = mfma16(aU[m].b, Blo[nb * 2 + 1], acc[m][nb]);
                }
#pragma unroll
            for (int m = 0; m < 2; m++)
#pragma unroll
                for (int nb = 0; nb < 4; nb++)
#pragma unroll
                    for (int r = 0; r < 4; r++) {
                        float y = acc[m][nb][r];
                        s[nb] += y; q[nb] += y * y;
                    }
        }
    }
#pragma unroll
    for (int nb = 0; nb < 4; nb++) {
        s[nb] += __shfl_xor(s[nb], 16); s[nb] += __shfl_xor(s[nb], 32);
        q[nb] += __shfl_xor(q[nb], 16); q[nb] += __shfl_xor(q[nb], 32);
    }
    if (lane < 16) {
#pragma unroll
        for (int nb = 0; nb < 4; nb++) {
            int ch = cb + nb * 16 + lane;
            fl[rowSel * 128 + ch]       = s[nb];
            fl[256 + rowSel * 128 + ch] = q[nb];
        }
    }
    __syncthreads();
    if (t < 128)
        sPart[(size_t)t * NBA + blockIdx.x] = fl[t] + fl[128 + t];
    else {
        int ch = t - 128;
        sPart[(size_t)(128 + ch) * NBA + blockIdx.x] = fl[256 + ch] + fl[384 + ch];
    }
}

// ---------------------------------------------------------------- reduce stat partials
__global__ void k_red1(const float* __restrict__ part, float* __restrict__ stats1)
{
    __shared__ float red[4];
    int o = blockIdx.x, t = threadIdx.x;
    float s = 0.0f;
    for (int k = t; k < NBA; k += 256) s += part[(size_t)o * NBA + k];
#pragma unroll
    for (int m = 1; m < 64; m <<= 1) s += __shfl_xor(s, m);
    if ((t & 63) == 0) red[t >> 6] = s;
    __syncthreads();
    if (t == 0) stats1[o] = red[0] + red[1] + red[2] + red[3];
}

// ---------------------------------------------------------------- kB: MFMA GEMM + BN1 + ReLU + voxel gather-max (final)
__global__ __launch_bounds__(256)
void kB_mapply(const uint16_t* __restrict__ XpL, const uint16_t* __restrict__ xmaxV,
               const float* __restrict__ w1, const int* __restrict__ vS,
               const int* __restrict__ vOff, const int* __restrict__ vCnt,
               const int* __restrict__ np, const float* __restrict__ sb1,
               float* __restrict__ outF, int ntiles)
{
    __shared__ uint16_t els[64 * ELS2];  // final relu(bn1(y)) bf16, stride 132
    int t = threadIdx.x;
    int wv = t >> 6, lane = t & 63;
    int l15 = lane & 15, lg = lane >> 4;
    int rowSel = wv & 1, cb = (wv >> 1) * 64;

    bf16x8 Bhi[8], Blo[8];
    load_wsplit(w1, cb, l15, lg, Bhi, Blo);

    float sc[4], bc[4];
#pragma unroll
    for (int nb = 0; nb < 4; nb++) {
        int c = cb + nb * 16 + l15;
        sc[nb] = sb1[c];
        bc[nb] = sb1[128 + c];
    }

    int nv = *np;
    int cg = t & 127, slot = t >> 7;

    for (int tile = blockIdx.x; tile < ntiles; tile += gridDim.x) {
        int tb = tile * 64;
        if (tb >= nv) break;             // uniform across block
        U8 aL[2], aU[2];
        load_afrags(XpL, xmaxV, vS, tb, rowSel, l15, lg, aL, aU);
        f32x4 acc[2][4];
#pragma unroll
        for (int m = 0; m < 2; m++)
#pragma unroll
            for (int nb = 0; nb < 4; nb++)
                acc[m][nb] = (f32x4){0.f, 0.f, 0.f, 0.f};
#pragma unroll
        for (int m = 0; m < 2; m++)
#pragma unroll
            for (int nb = 0; nb < 4; nb++) {
                acc[m][nb] = mfma16(aL[m].b, Bhi[nb * 2],     acc[m][nb]);
                acc[m][nb] = mfma16(aL[m].b, Blo[nb * 2],     acc[m][nb]);
                acc[m][nb] = mfma16(aU[m].b, Bhi[nb * 2 + 1], acc[m][nb]);
                acc[m][nb] = mfma16(aU[m].b, Blo[nb * 2 + 1], acc[m][nb]);
            }
        __syncthreads();                 // B1: prev tile's gather readers done
#pragma unroll
        for (int m = 0; m < 2; m++) {
            int rloc = rowSel * 32 + m * 16 + lg * 4;
#pragma unroll
            for (int nb = 0; nb < 4; nb++) {
                int c = cb + nb * 16 + l15;
#pragma unroll
                for (int r = 0; r < 4; r++) {
                    float e = fmaxf(acc[m][nb][r] * sc[nb] + bc[nb], 0.0f);
                    els[(rloc + r) * ELS2 + c] = f2b(e);
                }
            }
        }
        __syncthreads();                 // B2: els visible
        // voxel-driven gather (points sorted by voxel)
        int lastRow = nv - 1 - tb; if (lastRow > 63) lastRow = 63;
        int gFirst = vS[tb];
        int gLast  = vS[tb + lastRow];
        for (int g = gFirst + slot; g <= gLast; g += 2) {
            int offv = vOff[g], endv = offv + vCnt[g];
            int a  = offv > tb ? offv : tb;
            int e2 = endv < tb + 64 ? endv : tb + 64;
            float mx = 0.0f;
            for (int p = a; p < e2; p++)
                mx = fmaxf(mx, b2f(els[(p - tb) * ELS2 + cg]));
            size_t oa = (size_t)g * 128 + cg;
            if (offv >= tb && endv <= tb + 64) outF[oa] = mx;            // interior
            else if (mx > 0.0f)
                atomicMax((unsigned int*)&outF[oa], __float_as_uint(mx)); // straddler
        }
    }
}

// ---------------------------------------------------------------- launch
extern "C" void kernel_launch(void* const* d_in, const int* in_sizes, int n_in,
                              void* d_out, int out_size, void* d_ws, size_t ws_size,
                              hipStream_t stream)
{
    const float* pts = (const float*)d_in[0];
    const float* w0  = (const float*)d_in[1];
    const float* g0  = (const float*)d_in[2];
    const float* b0  = (const float*)d_in[3];
    const float* w1  = (const float*)d_in[4];
    const float* g1  = (const float*)d_in[5];
    const float* b1  = (const float*)d_in[6];

    int N      = in_sizes[0] / 5;
    int V      = out_size / 132;
    int Npad   = (N + 255) & ~255;
    int ntiles = Npad / 64;
    int nwin2  = (Npad + 127) / 128;

    char* ws = (char*)d_ws;
    size_t off = 0;
    auto alloc = [&](size_t bytes) { size_t r = off; off = (off + bytes + 255) & ~(size_t)255; return r; };

    int*    inv     = (int*)(ws + alloc((size_t)N * 4));
    int*    vS      = (int*)(ws + alloc((size_t)Npad * 4));
    size_t  zOff    = off;                                   // zero block start
    int*    cnt     = (int*)(ws + alloc((size_t)M_IDS * 4));
    int*    cursor  = (int*)(ws + alloc((size_t)M_IDS * 4));
    float*  stats   = (float*)(ws + alloc(320 * 4));         // bn0: 64 | bn1: 256
    int*    np      = (int*)(ws + alloc(4));
    float*  sums    = (float*)(ws + alloc((size_t)M_IDS * 16));
    size_t  zBytes  = off - zOff;
    int*    bOff    = (int*)(ws + alloc((size_t)M_IDS * 4));
    int*    idxArr  = (int*)(ws + alloc((size_t)M_IDS * 4));
    int*    vOff    = (int*)(ws + alloc((size_t)M_IDS * 4));
    int*    vCnt    = (int*)(ws + alloc((size_t)M_IDS * 4));
    int*    totO    = (int*)(ws + alloc(1024 * 4));
    int*    totC    = (int*)(ws + alloc(1024 * 4));
    int*    baseO   = (int*)(ws + alloc(1024 * 4));
    int*    baseC   = (int*)(ws + alloc(1024 * 4));
    float*  sb0     = (float*)(ws + alloc(64 * 4));
    float*  sb1     = (float*)(ws + alloc(256 * 4));
    float*  sPart   = (float*)(ws + alloc((size_t)256 * NBA * 4));
    float4* meanArr = (float4*)(ws + alloc((size_t)V * 16));
    uint16_t* XpL   = (uint16_t*)(ws + alloc((size_t)Npad * 32 * 2));
    uint16_t* xmaxV = (uint16_t*)(ws + alloc((size_t)V * 32 * 2));
    (void)ws_size;

    hipMemsetAsync(ws + zOff, 0, zBytes, stream);
    hipMemsetAsync(vS, 0xFF, (size_t)Npad * 4, stream);
    hipMemsetAsync(d_out, 0, (size_t)V * 128 * 4, stream);

    int blocksN = (N + 255) / 256;
    float* outF = (float*)d_out;

    k1_count<<<blocksN, 256, 0, stream>>>(pts, inv, cnt, sums, N);
    k2a_tot<<<NCHUNK, CH, 0, stream>>>(cnt, totO, totC, np);
    k2b_scan<<<1, 1024, 0, stream>>>(totO, totC, baseO, baseC);
    k2c_index<<<NCHUNK, CH, 0, stream>>>(cnt, baseO, baseC, sums, idxArr, bOff,
                                         vOff, vCnt, meanArr,
                                         outF + (size_t)V * 128);
    k35_feat<<<1024, 256, 0, stream>>>(pts, w0, inv, bOff, idxArr, meanArr,
                                       cursor, XpL, vS, stats, N);
    k_bnfin<<<1, 32, 0, stream>>>(stats, np, g0, b0, sb0, 32);
    k8_xmax<<<(V + 3) / 4, 256, 0, stream>>>(XpL, vOff, vCnt, sb0,
                                             (uint32_t*)xmaxV, V);
    kA_stats<<<NBA, 256, 0, stream>>>(XpL, xmaxV, w1, vS, np, sPart, nwin2);
    k_red1<<<256, 256, 0, stream>>>(sPart, stats + 64);
    k_bnfin<<<1, 128, 0, stream>>>(stats + 64, np, g1, b1, sb1, 128);
    kB_mapply<<<NBB, 256, 0, stream>>>(XpL, xmaxV, w1, vS, vOff, vCnt, np, sb1,
                                       outF, ntiles);
}

// Round 5
// 595.022 us; speedup vs baseline: 1.3761x; 1.2370x over previous
//
#include <hip/hip_runtime.h>
#include <cstdint>
#include <cstddef>

// ConvVFE: voxelize -> per-voxel mean -> MLP(10->32)+BN+ReLU -> voxel max
// -> concat -> MLP(64->128)+BN+ReLU -> voxel max ; plus voxel coords.
//
// R9: R8 counters: k1_count 191us, WRITE 128MB, VALU 0.7% -> the R7 float
// atomic xyz-sums in k1 are sector-granular RMW writebacks (~4 atomics/pt).
// kB (R8 back-end) dropped out of top-5 => back-end split worked.
// This round recombines the proven-best stage variants:
//  - k1: histogram only (R6 form; no inv, no sums).
//  - k3: payload scatter pts4+vS, voxel id recomputed inline (inv deleted).
//  - k4: contiguous per-voxel mean from sorted pts4 (R6 form, float4).
//  - k5: contiguous feature GEMM, raw y0 bf16 -> XpL + fused BN0 stats.
//  - k8/kA/kB: unchanged from R8 (BN0-writeback+xmaxV; streaming stats
//    GEMM; minimal MFMA apply + voxel gather-max, no k_final).

constexpr int M_IDS  = 220000;
constexpr int CH     = 256;
constexpr int NCHUNK = (M_IDS + CH - 1) / CH;   // 860
constexpr int NBA    = 1024;                    // kA grid / stats partials
constexpr int NBB    = 2048;                    // kB grid
constexpr int ELS2   = 132;                     // els row stride (u16)

typedef __attribute__((ext_vector_type(8))) __bf16          bf16x8;
typedef __attribute__((ext_vector_type(8))) unsigned short  u16x8;
typedef __attribute__((ext_vector_type(4))) float           f32x4;

union U8 { u16x8 u; bf16x8 b; };

__device__ __forceinline__ uint16_t f2b(float f) {
    uint32_t u = __float_as_uint(f);
    u += 0x7fffu + ((u >> 16) & 1u);
    return (uint16_t)(u >> 16);
}
__device__ __forceinline__ float b2f(uint16_t h) {
    return __uint_as_float(((uint32_t)h) << 16);
}

__device__ __forceinline__ f32x4 mfma16(bf16x8 a, bf16x8 b, f32x4 c) {
    return __builtin_amdgcn_mfma_f32_16x16x32_bf16(a, b, c, 0, 0, 0);
}

// ---------------------------------------------------------------- voxel id (shared by k1/k3)
__device__ __forceinline__ int voxel_id(const float* __restrict__ p) {
    float b = p[0], x = p[1], y = p[2], z = p[3];
    float fx = floorf((x - 0.0f) / 0.32f);
    float fy = floorf((y + 40.0f) / 0.32f);
    float fz = floorf((z + 3.0f) / 4.0f);
    bool ok = (fx >= 0.0f) && (fx < 220.0f) && (fy >= 0.0f) && (fy < 250.0f) &&
              (fz >= 0.0f) && (fz < 1.0f);
    if (!ok) return -1;
    return (int)b * 55000 + (int)fx * 250 + (int)fy + (int)fz;
}

// ---------------------------------------------------------------- k1: histogram only
__global__ void k1_count(const float* __restrict__ pts, int* __restrict__ cnt, int N)
{
    int i = blockIdx.x * blockDim.x + threadIdx.x;
    if (i >= N) return;
    int m = voxel_id(pts + (size_t)i * 5);
    if (m >= 0) atomicAdd(&cnt[m], 1);
}

// ---------------------------------------------------------------- k2: two-level scans
__global__ void k2a_tot(const int* __restrict__ cnt, int* __restrict__ totO,
                        int* __restrict__ totC, int* __restrict__ np)
{
    __shared__ int so[CH], sc[CH];
    int t = threadIdx.x;
    int id = blockIdx.x * CH + t;
    int c = (id < M_IDS) ? cnt[id] : 0;
    so[t] = (c > 0) ? 1 : 0;
    sc[t] = c;
    __syncthreads();
    for (int s = CH / 2; s > 0; s >>= 1) {
        if (t < s) { so[t] += so[t + s]; sc[t] += sc[t + s]; }
        __syncthreads();
    }
    if (t == 0) { totO[blockIdx.x] = so[0]; totC[blockIdx.x] = sc[0]; atomicAdd(np, sc[0]); }
}

__global__ void k2b_scan(const int* __restrict__ totO, const int* __restrict__ totC,
                         int* __restrict__ baseO, int* __restrict__ baseC)
{
    __shared__ int a[1024], bb[1024];
    int t = threadIdx.x;
    int vo = (t < NCHUNK) ? totO[t] : 0;
    int vc = (t < NCHUNK) ? totC[t] : 0;
    a[t] = vo; bb[t] = vc;
    __syncthreads();
    for (int off = 1; off < 1024; off <<= 1) {
        int xa = (t >= off) ? a[t - off] : 0;
        int xb = (t >= off) ? bb[t - off] : 0;
        __syncthreads();
        a[t] += xa; bb[t] += xb;
        __syncthreads();
    }
    baseO[t] = a[t] - vo;   // exclusive
    baseC[t] = bb[t] - vc;
}

__global__ void k2c_index(const int* __restrict__ cnt, const int* __restrict__ baseO,
                          const int* __restrict__ baseC, int* __restrict__ idxArr,
                          int* __restrict__ bOff, int* __restrict__ vOff,
                          int* __restrict__ vCnt, float* __restrict__ outCoords)
{
    __shared__ int a[CH], bb[CH];
    int t = threadIdx.x;
    int id = blockIdx.x * CH + t;
    int c = (id < M_IDS) ? cnt[id] : 0;
    int occ = (c > 0) ? 1 : 0;
    a[t] = occ; bb[t] = c;
    __syncthreads();
    for (int off = 1; off < CH; off <<= 1) {
        int xa = (t >= off) ? a[t - off] : 0;
        int xb = (t >= off) ? bb[t - off] : 0;
        __syncthreads();
        a[t] += xa; bb[t] += xb;
        __syncthreads();
    }
    if (id >= M_IDS) return;
    int g  = baseO[blockIdx.x] + a[t] - occ;
    int bo = baseC[blockIdx.x] + bb[t] - c;
    idxArr[id] = g;
    bOff[id]   = bo;
    if (occ) {
        vOff[g] = bo;
        vCnt[g] = c;
        int b2 = id / 55000;
        int rm = id % 55000;
        int cx = rm / 250;
        int cy = rm % 250;
        outCoords[(size_t)g * 4 + 0] = (float)b2;
        outCoords[(size_t)g * 4 + 1] = 0.0f;
        outCoords[(size_t)g * 4 + 2] = (float)cy;
        outCoords[(size_t)g * 4 + 3] = (float)cx;
    }
}

// ---------------------------------------------------------------- k3: scatter point payload to sorted order
__global__ void k3_order(const float* __restrict__ pts, const int* __restrict__ bOff,
                         const int* __restrict__ idxArr, int* __restrict__ cursor,
                         float4* __restrict__ pts4, int* __restrict__ vS, int N)
{
    int i = blockIdx.x * blockDim.x + threadIdx.x;
    if (i >= N) return;
    const float* p = pts + (size_t)i * 5;
    int m = voxel_id(p);
    if (m < 0) return;
    int slot = atomicAdd(&cursor[m], 1);
    int j = bOff[m] + slot;
    pts4[j] = make_float4(p[1], p[2], p[3], p[4]);
    vS[j]   = idxArr[m];
}

// ---------------------------------------------------------------- k4: per-voxel xyz mean (contiguous)
__global__ void k4_mean(const float4* __restrict__ pts4, const int* __restrict__ vOff,
                        const int* __restrict__ vCnt, float4* __restrict__ meanArr, int V)
{
    int g = blockIdx.x * blockDim.x + threadIdx.x;
    if (g >= V) return;
    int off = vOff[g], c = vCnt[g];
    float sx = 0.0f, sy = 0.0f, sz = 0.0f;
    for (int p = 0; p < c; p++) {
        float4 q = pts4[off + p];
        sx += q.x; sy += q.y; sz += q.z;
    }
    float ic = 1.0f / (float)c;
    meanArr[g] = make_float4(sx * ic, sy * ic, sz * ic, 0.0f);
}

// ---------------------------------------------------------------- k5: y0 = feats @ w0 (raw bf16, contiguous) + BN0 stats
__global__ __launch_bounds__(256)
void k5_y0(const float4* __restrict__ pts4, const float* __restrict__ w0,
           const int* __restrict__ vS, const float4* __restrict__ meanArr,
           uint16_t* __restrict__ XpL, float* __restrict__ stats0, int Npad)
{
    __shared__ float sl[64];
    int t = threadIdx.x;
    if (t < 64) sl[t] = 0.0f;
    __syncthreads();
    float s[32], q[32];
#pragma unroll
    for (int c = 0; c < 32; c++) { s[c] = 0.0f; q[c] = 0.0f; }

    for (int j = blockIdx.x * 256 + t; j < Npad; j += gridDim.x * 256) {
        int v = vS[j];
        if (v < 0) continue;             // pad/invalid rows: never read (vS guard)
        float4 P = pts4[j];
        float4 mn = meanArr[v];
        float x = P.x, y = P.y, z = P.z, it = P.w;
        float fx = floorf(x / 0.32f);
        float fy = floorf((y + 40.0f) / 0.32f);
        float f[10];
        f[0] = x; f[1] = y; f[2] = z; f[3] = it;
        f[4] = x - mn.x; f[5] = y - mn.y; f[6] = z - mn.z;
        f[7] = x - (fx * 0.32f + 0.16f);
        f[8] = y - (fy * 0.32f - 39.84f);
        f[9] = z + 1.0f;
        float y0[32];
#pragma unroll
        for (int c = 0; c < 32; c++) y0[c] = 0.0f;
#pragma unroll
        for (int d = 0; d < 10; d++) {
            float fd = f[d];
#pragma unroll
            for (int c = 0; c < 32; c++) y0[c] += fd * w0[d * 32 + c];
        }
        uint32_t pk[16];
#pragma unroll
        for (int k = 0; k < 16; k++)
            pk[k] = (uint32_t)f2b(y0[2 * k]) | ((uint32_t)f2b(y0[2 * k + 1]) << 16);
        uint4* rp = (uint4*)(XpL + (size_t)j * 32);
        rp[0] = make_uint4(pk[0], pk[1], pk[2], pk[3]);
        rp[1] = make_uint4(pk[4], pk[5], pk[6], pk[7]);
        rp[2] = make_uint4(pk[8], pk[9], pk[10], pk[11]);
        rp[3] = make_uint4(pk[12], pk[13], pk[14], pk[15]);
#pragma unroll
        for (int c = 0; c < 32; c++) { s[c] += y0[c]; q[c] += y0[c] * y0[c]; }
    }

    int lane = t & 63;
#pragma unroll
    for (int c = 0; c < 32; c++) {
#pragma unroll
        for (int m2 = 1; m2 < 64; m2 <<= 1) {
            s[c] += __shfl_xor(s[c], m2);
            q[c] += __shfl_xor(q[c], m2);
        }
        if (lane == c) { atomicAdd(&sl[c], s[c]); atomicAdd(&sl[32 + c], q[c]); }
    }
    __syncthreads();
    if (t < 64) atomicAdd(&stats0[t], sl[t]);
}

// ---------------------------------------------------------------- BN finalize
__global__ void k_bnfin(const float* __restrict__ stats, const int* __restrict__ np,
                        const float* __restrict__ g, const float* __restrict__ b,
                        float* __restrict__ sb, int C)
{
    int c = blockIdx.x * blockDim.x + threadIdx.x;
    if (c >= C) return;
    float n   = (float)(*np);
    float mu  = stats[c] / n;
    float var = stats[C + c] / n - mu * mu;
    float s   = g[c] / sqrtf(var + 1e-3f);
    sb[c]     = s;
    sb[C + c] = b[c] - mu * s;
}

// ---------------------------------------------------------------- k8: BN0 apply (writeback) + voxel max -> xmaxV
__global__ __launch_bounds__(256)
void k8_xmax(uint16_t* __restrict__ XpL, const int* __restrict__ vOff,
             const int* __restrict__ vCnt, const float* __restrict__ sb0,
             uint32_t* __restrict__ xmaxV, int V)
{
    int t = threadIdx.x;
    int g = blockIdx.x * 4 + (t >> 6);
    if (g >= V) return;
    int lane = t & 63;
    int c2 = lane & 15, h = lane >> 4;   // c2: u32 pair of channels, h: row phase
    int ch0 = c2 * 2;
    float sA = sb0[ch0],     bA = sb0[32 + ch0];
    float sB = sb0[ch0 + 1], bB = sb0[33 + ch0];
    int off = vOff[g], n = vCnt[g];
    float m0 = 0.0f, m1 = 0.0f;          // relu >= 0
    for (int i = h; i < n; i += 4) {
        uint32_t* ap = (uint32_t*)(XpL + (size_t)(off + i) * 32 + ch0);
        uint32_t u = *ap;
        float e0 = fmaxf(b2f((uint16_t)u) * sA + bA, 0.0f);
        float e1 = fmaxf(b2f((uint16_t)(u >> 16)) * sB + bB, 0.0f);
        *ap = (uint32_t)f2b(e0) | ((uint32_t)f2b(e1) << 16);
        m0 = fmaxf(m0, e0);
        m1 = fmaxf(m1, e1);
    }
    m0 = fmaxf(m0, __shfl_xor(m0, 16)); m0 = fmaxf(m0, __shfl_xor(m0, 32));
    m1 = fmaxf(m1, __shfl_xor(m1, 16)); m1 = fmaxf(m1, __shfl_xor(m1, 32));
    if (h == 0)
        xmaxV[(size_t)g * 16 + c2] = (uint32_t)f2b(m0) | ((uint32_t)f2b(m1) << 16);
}

// ---------------------------------------------------------------- W frags: bf16 hi/lo split of w1
__device__ __forceinline__ void load_wsplit(const float* __restrict__ w1, int cb,
                                            int l15, int lg, bf16x8* Bhi, bf16x8* Blo)
{
    int col = cb + l15;
    int kr  = lg * 8;
#pragma unroll
    for (int nb = 0; nb < 4; nb++) {
#pragma unroll
        for (int ks = 0; ks < 2; ks++) {
            U8 h, l;
#pragma unroll
            for (int jj = 0; jj < 8; jj++) {
                float w = w1[(ks * 32 + kr + jj) * 128 + col + nb * 16];
                uint16_t hb = f2b(w);
                h.u[jj] = hb;
                l.u[jj] = f2b(w - b2f(hb));
            }
            Bhi[nb * 2 + ks] = h.b;
            Blo[nb * 2 + ks] = l.b;
        }
    }
}

// ---------------------------------------------------------------- frag fetch (lower from XpL, upper from xmaxV via vS)
__device__ __forceinline__ void load_afrags(const uint16_t* __restrict__ XpL,
                                            const uint16_t* __restrict__ xmaxV,
                                            const int* __restrict__ vS,
                                            int tb, int rowSel, int l15, int lg,
                                            U8* aL, U8* aU)
{
#pragma unroll
    for (int m = 0; m < 2; m++) {
        int r = tb + rowSel * 32 + m * 16 + l15;
        int v = vS[r];                   // pad rows: -1 (memset)
        if (v >= 0) {
            aL[m].u = *(const u16x8*)(XpL + (size_t)r * 32 + lg * 8);
            aU[m].u = *(const u16x8*)(xmaxV + (size_t)v * 32 + lg * 8);
        } else {
#pragma unroll
            for (int j = 0; j < 8; j++) { aL[m].u[j] = 0; aU[m].u[j] = 0; }
        }
    }
}

// ---------------------------------------------------------------- kA: streaming stats GEMM (no barriers in loop)
__global__ __launch_bounds__(256)
void kA_stats(const uint16_t* __restrict__ XpL, const uint16_t* __restrict__ xmaxV,
              const float* __restrict__ w1, const int* __restrict__ vS,
              const int* __restrict__ np, float* __restrict__ sPart, int nwin2)
{
    __shared__ float fl[512];
    int t = threadIdx.x;
    int wv = t >> 6, lane = t & 63;
    int l15 = lane & 15, lg = lane >> 4;
    int rowSel = wv & 1, cb = (wv >> 1) * 64;

    bf16x8 Bhi[8], Blo[8];
    load_wsplit(w1, cb, l15, lg, Bhi, Blo);

    int nv = *np;
    float s[4] = {0.f, 0.f, 0.f, 0.f}, q[4] = {0.f, 0.f, 0.f, 0.f};

    for (int win = blockIdx.x; win < nwin2; win += gridDim.x) {
        int wb = win * 128;
        if (wb >= nv) break;
#pragma unroll
        for (int sub = 0; sub < 2; sub++) {
            int tb = wb + sub * 64;
            U8 aL[2], aU[2];
            load_afrags(XpL, xmaxV, vS, tb, rowSel, l15, lg, aL, aU);
            f32x4 acc[2][4];
#pragma unroll
            for (int m = 0; m < 2; m++)
#pragma unroll
                for (int nb = 0; nb < 4; nb++)
                    acc[m][nb] = (f32x4){0.f, 0.f, 0.f, 0.f};
#pragma unroll
            for (int m = 0; m < 2; m++)
#pragma unroll
                for (int nb = 0; nb < 4; nb++) {
                    acc[m][nb] = mfma16(aL[m].b, Bhi[nb * 2],     acc[m][nb]);
                    acc[m][nb] = mfma16(aL[m].b, Blo[nb * 2],     acc[m][nb]);
                    acc[m][nb] = mfma16(aU[m].b, Bhi[nb * 2 + 1], acc[m][nb]);
                    acc[m][nb] = mfma16(aU[m].b, Blo[nb * 2 + 1], acc[m][nb]);
                }
#pragma unroll
            for (int m = 0; m < 2; m++)
#pragma unroll
                for (int nb = 0; nb < 4; nb++)
#pragma unroll
                    for (int r = 0; r < 4; r++) {
                        float y = acc[m][nb][r];
                        s[nb] += y; q[nb] += y * y;
                    }
        }
    }
#pragma unroll
    for (int nb = 0; nb < 4; nb++) {
        s[nb] += __shfl_xor(s[nb], 16); s[nb] += __shfl_xor(s[nb], 32);
        q[nb] += __shfl_xor(q[nb], 16); q[nb] += __shfl_xor(q[nb], 32);
    }
    if (lane < 16) {
#pragma unroll
        for (int nb = 0; nb < 4; nb++) {
            int ch = cb + nb * 16 + lane;
            fl[rowSel * 128 + ch]       = s[nb];
            fl[256 + rowSel * 128 + ch] = q[nb];
        }
    }
    __syncthreads();
    if (t < 128)
        sPart[(size_t)t * NBA + blockIdx.x] = fl[t] + fl[128 + t];
    else {
        int ch = t - 128;
        sPart[(size_t)(128 + ch) * NBA + blockIdx.x] = fl[256 + ch] + fl[384 + ch];
    }
}

// ---------------------------------------------------------------- reduce stat partials
__global__ void k_red1(const float* __restrict__ part, float* __restrict__ stats1)
{
    __shared__ float red[4];
    int o = blockIdx.x, t = threadIdx.x;
    float s = 0.0f;
    for (int k = t; k < NBA; k += 256) s += part[(size_t)o * NBA + k];
#pragma unroll
    for (int m = 1; m < 64; m <<= 1) s += __shfl_xor(s, m);
    if ((t & 63) == 0) red[t >> 6] = s;
    __syncthreads();
    if (t == 0) stats1[o] = red[0] + red[1] + red[2] + red[3];
}

// ---------------------------------------------------------------- kB: MFMA GEMM + BN1 + ReLU + voxel gather-max (final)
__global__ __launch_bounds__(256)
void kB_mapply(const uint16_t* __restrict__ XpL, const uint16_t* __restrict__ xmaxV,
               const float* __restrict__ w1, const int* __restrict__ vS,
               const int* __restrict__ vOff, const int* __restrict__ vCnt,
               const int* __restrict__ np, const float* __restrict__ sb1,
               float* __restrict__ outF, int ntiles)
{
    __shared__ uint16_t els[64 * ELS2];  // final relu(bn1(y)) bf16, stride 132
    int t = threadIdx.x;
    int wv = t >> 6, lane = t & 63;
    int l15 = lane & 15, lg = lane >> 4;
    int rowSel = wv & 1, cb = (wv >> 1) * 64;

    bf16x8 Bhi[8], Blo[8];
    load_wsplit(w1, cb, l15, lg, Bhi, Blo);

    float sc[4], bc[4];
#pragma unroll
    for (int nb = 0; nb < 4; nb++) {
        int c = cb + nb * 16 + l15;
        sc[nb] = sb1[c];
        bc[nb] = sb1[128 + c];
    }

    int nv = *np;
    int cg = t & 127, slot = t >> 7;

    for (int tile = blockIdx.x; tile < ntiles; tile += gridDim.x) {
        int tb = tile * 64;
        if (tb >= nv) break;             // uniform across block
        U8 aL[2], aU[2];
        load_afrags(XpL, xmaxV, vS, tb, rowSel, l15, lg, aL, aU);
        f32x4 acc[2][4];
#pragma unroll
        for (int m = 0; m < 2; m++)
#pragma unroll
            for (int nb = 0; nb < 4; nb++)
                acc[m][nb] = (f32x4){0.f, 0.f, 0.f, 0.f};
#pragma unroll
        for (int m = 0; m < 2; m++)
#pragma unroll
            for (int nb = 0; nb < 4; nb++) {
                acc[m][nb] = mfma16(aL[m].b, Bhi[nb * 2],     acc[m][nb]);
                acc[m][nb] = mfma16(aL[m].b, Blo[nb * 2],     acc[m][nb]);
                acc[m][nb] = mfma16(aU[m].b, Bhi[nb * 2 + 1], acc[m][nb]);
                acc[m][nb] = mfma16(aU[m].b, Blo[nb * 2 + 1], acc[m][nb]);
            }
        __syncthreads();                 // B1: prev tile's gather readers done
#pragma unroll
        for (int m = 0; m < 2; m++) {
            int rloc = rowSel * 32 + m * 16 + lg * 4;
#pragma unroll
            for (int nb = 0; nb < 4; nb++) {
                int c = cb + nb * 16 + l15;
#pragma unroll
                for (int r = 0; r < 4; r++) {
                    float e = fmaxf(acc[m][nb][r] * sc[nb] + bc[nb], 0.0f);
                    els[(rloc + r) * ELS2 + c] = f2b(e);
                }
            }
        }
        __syncthreads();                 // B2: els visible
        // voxel-driven gather (points sorted by voxel)
        int lastRow = nv - 1 - tb; if (lastRow > 63) lastRow = 63;
        int gFirst = vS[tb];
        int gLast  = vS[tb + lastRow];
        for (int g = gFirst + slot; g <= gLast; g += 2) {
            int offv = vOff[g], endv = offv + vCnt[g];
            int a  = offv > tb ? offv : tb;
            int e2 = endv < tb + 64 ? endv : tb + 64;
            float mx = 0.0f;
            for (int p = a; p < e2; p++)
                mx = fmaxf(mx, b2f(els[(p - tb) * ELS2 + cg]));
            size_t oa = (size_t)g * 128 + cg;
            if (offv >= tb && endv <= tb + 64) outF[oa] = mx;            // interior
            else if (mx > 0.0f)
                atomicMax((unsigned int*)&outF[oa], __float_as_uint(mx)); // straddler
        }
    }
}

// ---------------------------------------------------------------- launch
extern "C" void kernel_launch(void* const* d_in, const int* in_sizes, int n_in,
                              void* d_out, int out_size, void* d_ws, size_t ws_size,
                              hipStream_t stream)
{
    const float* pts = (const float*)d_in[0];
    const float* w0  = (const float*)d_in[1];
    const float* g0  = (const float*)d_in[2];
    const float* b0  = (const float*)d_in[3];
    const float* w1  = (const float*)d_in[4];
    const float* g1  = (const float*)d_in[5];
    const float* b1  = (const float*)d_in[6];

    int N      = in_sizes[0] / 5;
    int V      = out_size / 132;
    int Npad   = (N + 255) & ~255;
    int ntiles = Npad / 64;
    int nwin2  = (Npad + 127) / 128;

    char* ws = (char*)d_ws;
    size_t off = 0;
    auto alloc = [&](size_t bytes) { size_t r = off; off = (off + bytes + 255) & ~(size_t)255; return r; };

    float4* pts4    = (float4*)(ws + alloc((size_t)Npad * 16));
    int*    vS      = (int*)(ws + alloc((size_t)Npad * 4));
    size_t  zOff    = off;                                   // zero block start
    int*    cnt     = (int*)(ws + alloc((size_t)M_IDS * 4));
    int*    cursor  = (int*)(ws + alloc((size_t)M_IDS * 4));
    float*  stats   = (float*)(ws + alloc(320 * 4));         // bn0: 64 | bn1: 256
    int*    np      = (int*)(ws + alloc(4));
    size_t  zBytes  = off - zOff;
    int*    bOff    = (int*)(ws + alloc((size_t)M_IDS * 4));
    int*    idxArr  = (int*)(ws + alloc((size_t)M_IDS * 4));
    int*    vOff    = (int*)(ws + alloc((size_t)M_IDS * 4));
    int*    vCnt    = (int*)(ws + alloc((size_t)M_IDS * 4));
    int*    totO    = (int*)(ws + alloc(1024 * 4));
    int*    totC    = (int*)(ws + alloc(1024 * 4));
    int*    baseO   = (int*)(ws + alloc(1024 * 4));
    int*    baseC   = (int*)(ws + alloc(1024 * 4));
    float*  sb0     = (float*)(ws + alloc(64 * 4));
    float*  sb1     = (float*)(ws + alloc(256 * 4));
    float*  sPart   = (float*)(ws + alloc((size_t)256 * NBA * 4));
    float4* meanArr = (float4*)(ws + alloc((size_t)V * 16));
    uint16_t* XpL   = (uint16_t*)(ws + alloc((size_t)Npad * 32 * 2));
    uint16_t* xmaxV = (uint16_t*)(ws + alloc((size_t)V * 32 * 2));
    (void)ws_size;

    hipMemsetAsync(ws + zOff, 0, zBytes, stream);
    hipMemsetAsync(vS, 0xFF, (size_t)Npad * 4, stream);
    hipMemsetAsync(d_out, 0, (size_t)V * 128 * 4, stream);

    int blocksN = (N + 255) / 256;
    float* outF = (float*)d_out;

    k1_count<<<blocksN, 256, 0, stream>>>(pts, cnt, N);
    k2a_tot<<<NCHUNK, CH, 0, stream>>>(cnt, totO, totC, np);
    k2b_scan<<<1, 1024, 0, stream>>>(totO, totC, baseO, baseC);
    k2c_index<<<NCHUNK, CH, 0, stream>>>(cnt, baseO, baseC, idxArr, bOff, vOff, vCnt,
                                         outF + (size_t)V * 128);
    k3_order<<<blocksN, 256, 0, stream>>>(pts, bOff, idxArr, cursor, pts4, vS, N);
    k4_mean<<<(V + 255) / 256, 256, 0, stream>>>(pts4, vOff, vCnt, meanArr, V);
    k5_y0<<<1024, 256, 0, stream>>>(pts4, w0, vS, meanArr, XpL, stats, Npad);
    k_bnfin<<<1, 32, 0, stream>>>(stats, np, g0, b0, sb0, 32);
    k8_xmax<<<(V + 3) / 4, 256, 0, stream>>>(XpL, vOff, vCnt, sb0,
                                             (uint32_t*)xmaxV, V);
    kA_stats<<<NBA, 256, 0, stream>>>(XpL, xmaxV, w1, vS, np, sPart, nwin2);
    k_red1<<<256, 256, 0, stream>>>(sPart, stats + 64);
    k_bnfin<<<1, 128, 0, stream>>>(stats + 64, np, g1, b1, sb1, 128);
    kB_mapply<<<NBB, 256, 0, stream>>>(XpL, xmaxV, w1, vS, vOff, vCnt, np, sb1,
                                       outF, ntiles);
}